// Round 7
// baseline (852.286 us; speedup 1.0000x reference)
//
#include <hip/hip_runtime.h>

typedef unsigned short u16;
typedef __attribute__((ext_vector_type(8))) short short8v;
typedef __attribute__((ext_vector_type(4))) float f32x4;

__device__ __forceinline__ u16 f2b(float f) {
  union { float fv; unsigned int i; } v; v.fv = f;
  unsigned int x = v.i;
  return (u16)((x + 0x7FFFu + ((x >> 16) & 1u)) >> 16);
}
__device__ __forceinline__ float blo(unsigned u) {
  union { unsigned i; float f; } v; v.i = u << 16; return v.f;
}
__device__ __forceinline__ float bhi(unsigned u) {
  union { unsigned i; float f; } v; v.i = u & 0xFFFF0000u; return v.f;
}

// ---------------- weight + emb prep (one launch) ----------------
__global__ __launch_bounds__(256) void k_prepw_all(
    const float* __restrict__ Wp, const float* __restrict__ W1a,
    const float* __restrict__ W2a, const float* __restrict__ W1b,
    const float* __restrict__ W2b, const float* __restrict__ emb,
    u16* __restrict__ Wpt, u16* __restrict__ W1at, u16* __restrict__ W2at,
    u16* __restrict__ W1bt, u16* __restrict__ W2bt, u16* __restrict__ embb)
{
  int idx = blockIdx.x * 256 + threadIdx.x;
  if (idx < 512 * 128) {
    int k = idx >> 7, c = idx & 127;
    Wpt[(size_t)c * 512 + k] = f2b(Wp[idx]);
    return;
  }
  idx -= 512 * 128;
  if (idx < 4 * 128 * 128) {
    int w = idx >> 14, r = idx & (128 * 128 - 1);
    int k = r >> 7, c = r & 127;
    const float* s = (w == 0) ? W1a : (w == 1) ? W2a : (w == 2) ? W1b : W2b;
    u16* d = (w == 0) ? W1at : (w == 1) ? W2at : (w == 2) ? W1bt : W2bt;
    d[(size_t)c * 128 + k] = f2b(s[r]);
    return;
  }
  idx -= 4 * 128 * 128;
  if (idx < 100 * 128) embb[idx] = f2b(emb[idx]);
}

// ---------------- MFMA GEMM, BM=64: out[N,128] = A[N,KTOT] @ W[KTOT,128] ----
// STAGE: 0 = A fp32, 1 = A fp32 + agg, 2 = A bf16
// EPI:   0 = f32 out (+bf16 if WB), 1 = relu -> bf16 out, 2 = (+xres) -> f32 (+bf16 if WB)
template <int KTOT, int STAGE, int EPI, bool WB>
__global__ __launch_bounds__(256) void k_gemm(
    const void* __restrict__ Ain, const float* __restrict__ agg,
    const u16* __restrict__ Wt, const float* __restrict__ bias,
    const float* __restrict__ xres, void* __restrict__ outp,
    u16* __restrict__ outb, int N)
{
  __shared__ u16 As[64 * 64];    // [r][k0..k0+64), row stride 128B, ^((r&7)<<4)
  __shared__ u16 Bs[128 * 64];
  const int t = threadIdx.x;
  const int row0 = blockIdx.x * 64;
  const int lane = t & 63;
  const int wave = t >> 6;
  const int wm = wave >> 1, wn = wave & 1;   // 2x2 waves: 32 rows x 64 cols each
  const int colg = lane & 15, rowg = lane >> 4;

  f32x4 acc[2][4];
#pragma unroll
  for (int ni = 0; ni < 4; ++ni) {
    float bc = bias[wn * 64 + ni * 16 + colg];
#pragma unroll
    for (int mi = 0; mi < 2; ++mi) acc[mi][ni] = (f32x4){bc, bc, bc, bc};
  }

  for (int k0 = 0; k0 < KTOT; k0 += 64) {
    if (STAGE <= 1) {
      const float* A = (const float*)Ain;
#pragma unroll
      for (int i = 0; i < 4; ++i) {
        int idx = t + i * 256;            // 1024 float4 = 64 rows x 16
        int r = idx >> 4, kq = idx & 15;
        float4 v = make_float4(0.f, 0.f, 0.f, 0.f);
        if (row0 + r < N) {
          v = *reinterpret_cast<const float4*>(A + (size_t)(row0 + r) * KTOT + k0 + kq * 4);
          if (STAGE == 1) {
            float4 av = *reinterpret_cast<const float4*>(agg + (size_t)(row0 + r) * 128 + k0 + kq * 4);
            v.x += av.x; v.y += av.y; v.z += av.z; v.w += av.w;
          }
        }
        ushort4 b;
        b.x = f2b(v.x); b.y = f2b(v.y); b.z = f2b(v.z); b.w = f2b(v.w);
        int byteoff = (r * 128 + kq * 8) ^ ((r & 7) << 4);
        *reinterpret_cast<ushort4*>((char*)As + byteoff) = b;
      }
    } else {
      const u16* A = (const u16*)Ain;
#pragma unroll
      for (int i = 0; i < 2; ++i) {
        int idx = t + i * 256;            // 512 int4 = 64 rows x 8
        int r = idx >> 3, k8 = idx & 7;
        int4 v = make_int4(0, 0, 0, 0);
        if (row0 + r < N)
          v = *reinterpret_cast<const int4*>(A + (size_t)(row0 + r) * KTOT + k0 + k8 * 8);
        int byteoff = (r * 128 + k8 * 16) ^ ((r & 7) << 4);
        *reinterpret_cast<int4*>((char*)As + byteoff) = v;
      }
    }
#pragma unroll
    for (int i = 0; i < 4; ++i) {
      int idx = t + i * 256;              // 1024 int4 = 128 cols x 8
      int c = idx >> 3, k8 = idx & 7;
      int4 v = *reinterpret_cast<const int4*>(Wt + (size_t)c * KTOT + k0 + k8 * 8);
      int byteoff = (c * 128 + k8 * 16) ^ ((c & 7) << 4);
      *reinterpret_cast<int4*>((char*)Bs + byteoff) = v;
    }
    __syncthreads();
#pragma unroll
    for (int kk = 0; kk < 64; kk += 32) {
      short8v a[2], b[4];
#pragma unroll
      for (int mi = 0; mi < 2; ++mi) {
        int r = wm * 32 + mi * 16 + colg;
        int byteoff = (r * 128 + (kk + rowg * 8) * 2) ^ ((r & 7) << 4);
        a[mi] = *reinterpret_cast<const short8v*>((const char*)As + byteoff);
      }
#pragma unroll
      for (int ni = 0; ni < 4; ++ni) {
        int c = wn * 64 + ni * 16 + colg;
        int byteoff = (c * 128 + (kk + rowg * 8) * 2) ^ ((c & 7) << 4);
        b[ni] = *reinterpret_cast<const short8v*>((const char*)Bs + byteoff);
      }
#pragma unroll
      for (int mi = 0; mi < 2; ++mi)
#pragma unroll
        for (int ni = 0; ni < 4; ++ni)
          acc[mi][ni] = __builtin_amdgcn_mfma_f32_16x16x32_bf16(a[mi], b[ni], acc[mi][ni], 0, 0, 0);
    }
    __syncthreads();
  }

#pragma unroll
  for (int mi = 0; mi < 2; ++mi) {
#pragma unroll
    for (int j = 0; j < 4; ++j) {
      int row = row0 + wm * 32 + mi * 16 + rowg * 4 + j;
      if (row >= N) continue;
#pragma unroll
      for (int ni = 0; ni < 4; ++ni) {
        int col = wn * 64 + ni * 16 + colg;
        float v = acc[mi][ni][j];
        if (EPI == 1) {
          ((u16*)outp)[(size_t)row * 128 + col] = f2b(fmaxf(v, 0.f));
        } else {
          if (EPI == 2) v += xres[(size_t)row * 128 + col];
          ((float*)outp)[(size_t)row * 128 + col] = v;
          if (WB) outb[(size_t)row * 128 + col] = f2b(v);
        }
      }
    }
  }
}

// ---------------- CSR build ----------------
__global__ __launch_bounds__(256) void k_hist(
    const int* __restrict__ dst, int* __restrict__ deg, int nE)
{
  int e = blockIdx.x * 256 + threadIdx.x;
  if (e < nE) atomicAdd(&deg[dst[e]], 1);
}

__global__ __launch_bounds__(256) void k_scanA(
    const int* __restrict__ deg, int* __restrict__ part, int N)
{
  const int b = blockIdx.x, t = threadIdx.x;
  const int lane = t & 63, wave = t >> 6;
  int base = b * 1024 + t * 4;
  int s = 0;
#pragma unroll
  for (int i = 0; i < 4; ++i) { int j = base + i; if (j < N) s += deg[j]; }
  int v = s;
  for (int d = 1; d < 64; d <<= 1) { int u = __shfl_up(v, d); if (lane >= d) v += u; }
  __shared__ int wsum[4];
  if (lane == 63) wsum[wave] = v;
  __syncthreads();
  if (t == 0) part[b] = wsum[0] + wsum[1] + wsum[2] + wsum[3];
}

__global__ __launch_bounds__(128) void k_scanB(
    int* __restrict__ part, int* __restrict__ off, int NB, int N)
{
  __shared__ int ps[128];
  const int t = threadIdx.x;
  int v0 = (t < NB) ? part[t] : 0;
  ps[t] = v0;
  __syncthreads();
  for (int d = 1; d < 128; d <<= 1) {
    int u = (t >= d) ? ps[t - d] : 0;
    __syncthreads();
    ps[t] += u;
    __syncthreads();
  }
  if (t < NB) part[t] = ps[t] - v0;
  if (t == 127) off[N] = ps[127];
}

__global__ __launch_bounds__(256) void k_scanC(
    const int* __restrict__ deg, const int* __restrict__ part,
    int* __restrict__ off, int N)
{
  const int b = blockIdx.x, t = threadIdx.x;
  const int lane = t & 63, wave = t >> 6;
  int base = b * 1024 + t * 4;
  int d0 = 0, d1 = 0, d2 = 0, d3 = 0;
  if (base + 0 < N) d0 = deg[base + 0];
  if (base + 1 < N) d1 = deg[base + 1];
  if (base + 2 < N) d2 = deg[base + 2];
  if (base + 3 < N) d3 = deg[base + 3];
  int s = d0 + d1 + d2 + d3;
  int v = s;
  for (int dd = 1; dd < 64; dd <<= 1) { int u = __shfl_up(v, dd); if (lane >= dd) v += u; }
  int excl = v - s;
  __shared__ int wsum[4];
  if (lane == 63) wsum[wave] = v;
  __syncthreads();
  int wbase = 0;
  for (int w = 0; w < wave; ++w) wbase += wsum[w];
  int run = part[b] + wbase + excl;
  if (base + 0 < N) { off[base + 0] = run; run += d0; }
  if (base + 1 < N) { off[base + 1] = run; run += d1; }
  if (base + 2 < N) { off[base + 2] = run; run += d2; }
  if (base + 3 < N) { off[base + 3] = run; run += d3; }
}

// btail[b] = off[b*128]  (bucket write tails for phase-1)
__global__ __launch_bounds__(256) void k_binit(
    const int* __restrict__ off, int* __restrict__ btail, int NBK)
{
  int b = blockIdx.x * 256 + threadIdx.x;
  if (b < NBK) btail[b] = off[b * 128];
}

// phase 1: bin edges into 128-node dst-buckets (contiguous regions of bspace).
// payload = src | attr<<17 | (dst&127)<<24  (17+7+7 = 31 bits)
__global__ __launch_bounds__(256) void k_p1(
    const int* __restrict__ src, const int* __restrict__ dst,
    const int* __restrict__ attr, int* __restrict__ btail,
    int* __restrict__ bspace, int nE)
{
  int e = blockIdx.x * 256 + threadIdx.x;
  if (e >= nE) return;
  int d = dst[e];
  int pos = atomicAdd(&btail[d >> 7], 1);
  bspace[pos] = src[e] | (attr[e] << 17) | ((d & 127) << 24);
}

// phase 2: one block per bucket; exact CSR position via LDS cursors seeded
// with off[]; writes confined to the bucket's contiguous ep region.
__global__ __launch_bounds__(256) void k_p2(
    const int* __restrict__ bspace, const int* __restrict__ off,
    int* __restrict__ ep, int N)
{
  __shared__ int lc[128];
  const int b = blockIdx.x, t = threadIdx.x;
  const int nb = b * 128;
  const int nn = min(128, N - nb);
  if (t < nn) lc[t] = off[nb + t];
  __syncthreads();
  const int base = off[nb];
  const int cnt = off[min(nb + 128, N)] - base;
  for (int i = t; i < cnt; i += 256) {
    int p = bspace[base + i];
    int ld = (p >> 24) & 127;
    int pos = atomicAdd(&lc[ld], 1);
    ep[pos] = p & 0xFFFFFF;
  }
}

// agg[i] = sum relu(xb[src] + embb[attr]); bf16 gather (256B rows), fp32 accum
__global__ __launch_bounds__(256) void k_agg(
    const u16* __restrict__ xb, const int* __restrict__ ep,
    const int* __restrict__ off, const u16* __restrict__ embb,
    float* __restrict__ agg, int N)
{
  const int node = blockIdx.x * 4 + (threadIdx.x >> 6);
  if (node >= N) return;
  const int lane = threadIdx.x & 63;
  const int beg = off[node], end = off[node + 1];
  float ax = 0.f, ay = 0.f;
  int e = beg;
  for (; e + 2 <= end; e += 2) {
    int p0 = ep[e], p1 = ep[e + 1];
    int s0 = p0 & 0x1FFFF, a0 = p0 >> 17;
    int s1 = p1 & 0x1FFFF, a1 = p1 >> 17;
    unsigned xu0 = *reinterpret_cast<const unsigned*>(xb + ((size_t)s0 << 7) + lane * 2);
    unsigned eu0 = *reinterpret_cast<const unsigned*>(embb + ((size_t)a0 << 7) + lane * 2);
    unsigned xu1 = *reinterpret_cast<const unsigned*>(xb + ((size_t)s1 << 7) + lane * 2);
    unsigned eu1 = *reinterpret_cast<const unsigned*>(embb + ((size_t)a1 << 7) + lane * 2);
    ax += fmaxf(blo(xu0) + blo(eu0), 0.f);
    ay += fmaxf(bhi(xu0) + bhi(eu0), 0.f);
    ax += fmaxf(blo(xu1) + blo(eu1), 0.f);
    ay += fmaxf(bhi(xu1) + bhi(eu1), 0.f);
  }
  if (e < end) {
    int p = ep[e];
    int s = p & 0x1FFFF, a = p >> 17;
    unsigned xu = *reinterpret_cast<const unsigned*>(xb + ((size_t)s << 7) + lane * 2);
    unsigned eu = *reinterpret_cast<const unsigned*>(embb + ((size_t)a << 7) + lane * 2);
    ax += fmaxf(blo(xu) + blo(eu), 0.f);
    ay += fmaxf(bhi(xu) + bhi(eu), 0.f);
  }
  float2* op = reinterpret_cast<float2*>(agg + (size_t)node * 128 + lane * 2);
  *op = make_float2(ax, ay);
}

// ---------------- launcher ----------------
extern "C" void kernel_launch(void* const* d_in, const int* in_sizes, int n_in,
                              void* d_out, int out_size, void* d_ws, size_t ws_size,
                              hipStream_t stream)
{
  const float* pept  = (const float*)d_in[0];
  const int*   eidx  = (const int*)d_in[1];
  const int*   eattr = (const int*)d_in[2];
  const float* Wp  = (const float*)d_in[3];
  const float* bp  = (const float*)d_in[4];
  const float* emb = (const float*)d_in[5];
  // d_in[6]=cls_token, d_in[7]=cls_edge: dead for the output (CLS node is never
  // a source and row N is dropped) -> skipped.
  const float* W1a = (const float*)d_in[8];
  const float* b1a = (const float*)d_in[9];
  const float* W2a = (const float*)d_in[10];
  const float* b2a = (const float*)d_in[11];
  const float* W1b = (const float*)d_in[12];
  const float* b1b = (const float*)d_in[13];
  const float* W2b = (const float*)d_in[14];
  const float* b2b = (const float*)d_in[15];

  const int N = in_sizes[0] / 512;
  const int E = in_sizes[1] / 2;
  const int* srcp = eidx;
  const int* dstp = eidx + E;

  char* ws = (char*)d_ws;
  const size_t rowBytes = (size_t)N * 128 * 4;
  float* agg = (float*)ws;                          // [N,128] f32
  float* x0  = (float*)(ws + rowBytes);             // [N,128] f32
  char*  p   = ws + 2 * rowBytes;
  u16* tbh   = (u16*)p;             p += (size_t)N * 128 * 2;   // bf16 hidden
  u16* xb    = (u16*)p;             p += (size_t)N * 128 * 2;   // bf16 x mirror
  int* deg    = (int*)p;            p += (size_t)(N + 1) * 4;
  int* off    = (int*)p;            p += (size_t)(N + 1) * 4;
  int* part   = (int*)p;            p += 128 * 4;
  int* btail  = (int*)p;            p += (size_t)((N + 127) / 128) * 4;
  int* ep     = (int*)p;            p += (size_t)E * 4;
  int* bspace = (int*)p;            p += (size_t)E * 4;
  u16* Wpt  = (u16*)p;              p += (size_t)512 * 128 * 2;
  u16* W1at = (u16*)p;              p += (size_t)128 * 128 * 2;
  u16* W2at = (u16*)p;              p += (size_t)128 * 128 * 2;
  u16* W1bt = (u16*)p;              p += (size_t)128 * 128 * 2;
  u16* W2bt = (u16*)p;              p += (size_t)128 * 128 * 2;
  u16* embb = (u16*)p;              p += (size_t)100 * 128 * 2;
  float* x1 = (float*)d_out;
  float* outp = (float*)d_out;

  const int gGemm = (N + 63) / 64;
  const int gE    = (E + 255) / 256;
  const int gAgg  = (N + 3) / 4;
  const int NBsc  = (N + 1023) / 1024;   // scan blocks
  const int NBK   = (N + 127) / 128;     // dst buckets

  hipLaunchKernelGGL(k_prepw_all,
                     dim3((512 * 128 + 4 * 128 * 128 + 100 * 128 + 255) / 256), dim3(256), 0, stream,
                     Wp, W1a, W2a, W1b, W2b, emb, Wpt, W1at, W2at, W1bt, W2bt, embb);

  // proj: x0 = pept @ Wp + bp  (also emits bf16 mirror xb)
  hipLaunchKernelGGL((k_gemm<512, 0, 0, true>), dim3(gGemm), dim3(256), 0, stream,
                     pept, (const float*)nullptr, Wpt, bp, (const float*)nullptr, x0, xb, N);

  // CSR by dst (built once, reused by both layers)
  hipMemsetAsync(deg, 0, (size_t)(N + 1) * 4, stream);
  hipLaunchKernelGGL(k_hist, dim3(gE), dim3(256), 0, stream, dstp, deg, E);
  hipLaunchKernelGGL(k_scanA, dim3(NBsc), dim3(256), 0, stream, deg, part, N);
  hipLaunchKernelGGL(k_scanB, dim3(1), dim3(128), 0, stream, part, off, NBsc, N);
  hipLaunchKernelGGL(k_scanC, dim3(NBsc), dim3(256), 0, stream, deg, part, off, N);
  hipLaunchKernelGGL(k_binit, dim3((NBK + 255) / 256), dim3(256), 0, stream, off, btail, NBK);
  hipLaunchKernelGGL(k_p1, dim3(gE), dim3(256), 0, stream,
                     srcp, dstp, eattr, btail, bspace, E);
  hipLaunchKernelGGL(k_p2, dim3(NBK), dim3(256), 0, stream, bspace, off, ep, N);

  // ---- layer a ----
  hipLaunchKernelGGL(k_agg, dim3(gAgg), dim3(256), 0, stream, xb, ep, off, embb, agg, N);
  hipLaunchKernelGGL((k_gemm<128, 1, 1, false>), dim3(gGemm), dim3(256), 0, stream,
                     x0, agg, W1at, b1a, (const float*)nullptr, tbh, (u16*)nullptr, N);
  hipLaunchKernelGGL((k_gemm<128, 2, 2, true>), dim3(gGemm), dim3(256), 0, stream,
                     tbh, (const float*)nullptr, W2at, b2a, x0, x1, xb, N);

  // ---- layer b ----
  hipLaunchKernelGGL(k_agg, dim3(gAgg), dim3(256), 0, stream, xb, ep, off, embb, agg, N);
  hipLaunchKernelGGL((k_gemm<128, 1, 1, false>), dim3(gGemm), dim3(256), 0, stream,
                     x1, agg, W1bt, b1b, (const float*)nullptr, tbh, (u16*)nullptr, N);
  hipLaunchKernelGGL((k_gemm<128, 2, 2, false>), dim3(gGemm), dim3(256), 0, stream,
                     tbh, (const float*)nullptr, W2bt, b2b, x1, outp, (u16*)nullptr, N);
}

// Round 8
// 525.919 us; speedup vs baseline: 1.6206x; 1.6206x over previous
//
#include <hip/hip_runtime.h>

typedef unsigned short u16;
typedef __attribute__((ext_vector_type(8))) short short8v;
typedef __attribute__((ext_vector_type(4))) float f32x4;

__device__ __forceinline__ u16 f2b(float f) {
  union { float fv; unsigned int i; } v; v.fv = f;
  unsigned int x = v.i;
  return (u16)((x + 0x7FFFu + ((x >> 16) & 1u)) >> 16);
}
__device__ __forceinline__ float blo(unsigned u) {
  union { unsigned i; float f; } v; v.i = u << 16; return v.f;
}
__device__ __forceinline__ float bhi(unsigned u) {
  union { unsigned i; float f; } v; v.i = u & 0xFFFF0000u; return v.f;
}

// ---------------- weight + emb prep (one launch) ----------------
__global__ __launch_bounds__(256) void k_prepw_all(
    const float* __restrict__ Wp, const float* __restrict__ W1a,
    const float* __restrict__ W2a, const float* __restrict__ W1b,
    const float* __restrict__ W2b, const float* __restrict__ emb,
    u16* __restrict__ Wpt, u16* __restrict__ W1at, u16* __restrict__ W2at,
    u16* __restrict__ W1bt, u16* __restrict__ W2bt, u16* __restrict__ embb)
{
  int idx = blockIdx.x * 256 + threadIdx.x;
  if (idx < 512 * 128) {
    int k = idx >> 7, c = idx & 127;
    Wpt[(size_t)c * 512 + k] = f2b(Wp[idx]);
    return;
  }
  idx -= 512 * 128;
  if (idx < 4 * 128 * 128) {
    int w = idx >> 14, r = idx & (128 * 128 - 1);
    int k = r >> 7, c = r & 127;
    const float* s = (w == 0) ? W1a : (w == 1) ? W2a : (w == 2) ? W1b : W2b;
    u16* d = (w == 0) ? W1at : (w == 1) ? W2at : (w == 2) ? W1bt : W2bt;
    d[(size_t)c * 128 + k] = f2b(s[r]);
    return;
  }
  idx -= 4 * 128 * 128;
  if (idx < 100 * 128) embb[idx] = f2b(emb[idx]);
}

// ---------------- MFMA GEMM, BM=64: out[N,128] = A[N,KTOT] @ W[KTOT,128] ----
// STAGE: 0 = A fp32, 1 = A fp32 + agg, 2 = A bf16
// EPI:   0 = f32 out (+bf16 if WB), 1 = relu -> bf16 out, 2 = (+xres) -> f32 (+bf16 if WB)
template <int KTOT, int STAGE, int EPI, bool WB>
__global__ __launch_bounds__(256) void k_gemm(
    const void* __restrict__ Ain, const float* __restrict__ agg,
    const u16* __restrict__ Wt, const float* __restrict__ bias,
    const float* __restrict__ xres, void* __restrict__ outp,
    u16* __restrict__ outb, int N)
{
  __shared__ u16 As[64 * 64];    // [r][k0..k0+64), row stride 128B, ^((r&7)<<4)
  __shared__ u16 Bs[128 * 64];
  const int t = threadIdx.x;
  const int row0 = blockIdx.x * 64;
  const int lane = t & 63;
  const int wave = t >> 6;
  const int wm = wave >> 1, wn = wave & 1;   // 2x2 waves: 32 rows x 64 cols each
  const int colg = lane & 15, rowg = lane >> 4;

  f32x4 acc[2][4];
#pragma unroll
  for (int ni = 0; ni < 4; ++ni) {
    float bc = bias[wn * 64 + ni * 16 + colg];
#pragma unroll
    for (int mi = 0; mi < 2; ++mi) acc[mi][ni] = (f32x4){bc, bc, bc, bc};
  }

  for (int k0 = 0; k0 < KTOT; k0 += 64) {
    if (STAGE <= 1) {
      const float* A = (const float*)Ain;
#pragma unroll
      for (int i = 0; i < 4; ++i) {
        int idx = t + i * 256;            // 1024 float4 = 64 rows x 16
        int r = idx >> 4, kq = idx & 15;
        float4 v = make_float4(0.f, 0.f, 0.f, 0.f);
        if (row0 + r < N) {
          v = *reinterpret_cast<const float4*>(A + (size_t)(row0 + r) * KTOT + k0 + kq * 4);
          if (STAGE == 1) {
            float4 av = *reinterpret_cast<const float4*>(agg + (size_t)(row0 + r) * 128 + k0 + kq * 4);
            v.x += av.x; v.y += av.y; v.z += av.z; v.w += av.w;
          }
        }
        ushort4 b;
        b.x = f2b(v.x); b.y = f2b(v.y); b.z = f2b(v.z); b.w = f2b(v.w);
        int byteoff = (r * 128 + kq * 8) ^ ((r & 7) << 4);
        *reinterpret_cast<ushort4*>((char*)As + byteoff) = b;
      }
    } else {
      const u16* A = (const u16*)Ain;
#pragma unroll
      for (int i = 0; i < 2; ++i) {
        int idx = t + i * 256;            // 512 int4 = 64 rows x 8
        int r = idx >> 3, k8 = idx & 7;
        int4 v = make_int4(0, 0, 0, 0);
        if (row0 + r < N)
          v = *reinterpret_cast<const int4*>(A + (size_t)(row0 + r) * KTOT + k0 + k8 * 8);
        int byteoff = (r * 128 + k8 * 16) ^ ((r & 7) << 4);
        *reinterpret_cast<int4*>((char*)As + byteoff) = v;
      }
    }
#pragma unroll
    for (int i = 0; i < 4; ++i) {
      int idx = t + i * 256;              // 1024 int4 = 128 cols x 8
      int c = idx >> 3, k8 = idx & 7;
      int4 v = *reinterpret_cast<const int4*>(Wt + (size_t)c * KTOT + k0 + k8 * 8);
      int byteoff = (c * 128 + k8 * 16) ^ ((c & 7) << 4);
      *reinterpret_cast<int4*>((char*)Bs + byteoff) = v;
    }
    __syncthreads();
#pragma unroll
    for (int kk = 0; kk < 64; kk += 32) {
      short8v a[2], b[4];
#pragma unroll
      for (int mi = 0; mi < 2; ++mi) {
        int r = wm * 32 + mi * 16 + colg;
        int byteoff = (r * 128 + (kk + rowg * 8) * 2) ^ ((r & 7) << 4);
        a[mi] = *reinterpret_cast<const short8v*>((const char*)As + byteoff);
      }
#pragma unroll
      for (int ni = 0; ni < 4; ++ni) {
        int c = wn * 64 + ni * 16 + colg;
        int byteoff = (c * 128 + (kk + rowg * 8) * 2) ^ ((c & 7) << 4);
        b[ni] = *reinterpret_cast<const short8v*>((const char*)Bs + byteoff);
      }
#pragma unroll
      for (int mi = 0; mi < 2; ++mi)
#pragma unroll
        for (int ni = 0; ni < 4; ++ni)
          acc[mi][ni] = __builtin_amdgcn_mfma_f32_16x16x32_bf16(a[mi], b[ni], acc[mi][ni], 0, 0, 0);
    }
    __syncthreads();
  }

#pragma unroll
  for (int mi = 0; mi < 2; ++mi) {
#pragma unroll
    for (int j = 0; j < 4; ++j) {
      int row = row0 + wm * 32 + mi * 16 + rowg * 4 + j;
      if (row >= N) continue;
#pragma unroll
      for (int ni = 0; ni < 4; ++ni) {
        int col = wn * 64 + ni * 16 + colg;
        float v = acc[mi][ni][j];
        if (EPI == 1) {
          ((u16*)outp)[(size_t)row * 128 + col] = f2b(fmaxf(v, 0.f));
        } else {
          if (EPI == 2) v += xres[(size_t)row * 128 + col];
          ((float*)outp)[(size_t)row * 128 + col] = v;
          if (WB) outb[(size_t)row * 128 + col] = f2b(v);
        }
      }
    }
  }
}

// ---------------- CSR build ----------------
__global__ __launch_bounds__(256) void k_hist(
    const int* __restrict__ dst, int* __restrict__ deg, int nE)
{
  int e = blockIdx.x * 256 + threadIdx.x;
  if (e < nE) atomicAdd(&deg[dst[e]], 1);
}

__global__ __launch_bounds__(256) void k_scanA(
    const int* __restrict__ deg, int* __restrict__ part, int N)
{
  const int b = blockIdx.x, t = threadIdx.x;
  const int lane = t & 63, wave = t >> 6;
  int base = b * 1024 + t * 4;
  int s = 0;
#pragma unroll
  for (int i = 0; i < 4; ++i) { int j = base + i; if (j < N) s += deg[j]; }
  int v = s;
  for (int d = 1; d < 64; d <<= 1) { int u = __shfl_up(v, d); if (lane >= d) v += u; }
  __shared__ int wsum[4];
  if (lane == 63) wsum[wave] = v;
  __syncthreads();
  if (t == 0) part[b] = wsum[0] + wsum[1] + wsum[2] + wsum[3];
}

__global__ __launch_bounds__(128) void k_scanB(
    int* __restrict__ part, int* __restrict__ off, int NB, int N)
{
  __shared__ int ps[128];
  const int t = threadIdx.x;
  int v0 = (t < NB) ? part[t] : 0;
  ps[t] = v0;
  __syncthreads();
  for (int d = 1; d < 128; d <<= 1) {
    int u = (t >= d) ? ps[t - d] : 0;
    __syncthreads();
    ps[t] += u;
    __syncthreads();
  }
  if (t < NB) part[t] = ps[t] - v0;
  if (t == 127) off[N] = ps[127];
}

__global__ __launch_bounds__(256) void k_scanC(
    const int* __restrict__ deg, const int* __restrict__ part,
    int* __restrict__ off, int N)
{
  const int b = blockIdx.x, t = threadIdx.x;
  const int lane = t & 63, wave = t >> 6;
  int base = b * 1024 + t * 4;
  int d0 = 0, d1 = 0, d2 = 0, d3 = 0;
  if (base + 0 < N) d0 = deg[base + 0];
  if (base + 1 < N) d1 = deg[base + 1];
  if (base + 2 < N) d2 = deg[base + 2];
  if (base + 3 < N) d3 = deg[base + 3];
  int s = d0 + d1 + d2 + d3;
  int v = s;
  for (int dd = 1; dd < 64; dd <<= 1) { int u = __shfl_up(v, dd); if (lane >= dd) v += u; }
  int excl = v - s;
  __shared__ int wsum[4];
  if (lane == 63) wsum[wave] = v;
  __syncthreads();
  int wbase = 0;
  for (int w = 0; w < wave; ++w) wbase += wsum[w];
  int run = part[b] + wbase + excl;
  if (base + 0 < N) { off[base + 0] = run; run += d0; }
  if (base + 1 < N) { off[base + 1] = run; run += d1; }
  if (base + 2 < N) { off[base + 2] = run; run += d2; }
  if (base + 3 < N) { off[base + 3] = run; run += d3; }
}

// btail[b] = off[b*128]  (bucket write tails for phase-1)
__global__ __launch_bounds__(256) void k_binit(
    const int* __restrict__ off, int* __restrict__ btail, int NBK)
{
  int b = blockIdx.x * 256 + threadIdx.x;
  if (b < NBK) btail[b] = off[b * 128];
}

// phase 1: bin edges into 128-node dst-buckets via per-block LDS histogram +
// ONE bulk atomic reservation per (block,bucket) -- kills same-address
// contention (round-7 lesson: 1.6M atomics on 782 addrs = 376us).
// payload = src | attr<<17 | (dst&127)<<24
#define P1_CHUNK 4096
__global__ __launch_bounds__(256) void k_p1(
    const int* __restrict__ src, const int* __restrict__ dst,
    const int* __restrict__ attr, int* __restrict__ btail,
    int* __restrict__ bspace, int nE, int NBK)
{
  __shared__ int lc[1024];          // NBK <= 1024 (N <= 131072)
  const int t = threadIdx.x;
  const int e0 = blockIdx.x * P1_CHUNK;
  const int e1 = min(e0 + P1_CHUNK, nE);
  for (int i = t; i < NBK; i += 256) lc[i] = 0;
  __syncthreads();
  for (int e = e0 + t; e < e1; e += 256) atomicAdd(&lc[dst[e] >> 7], 1);
  __syncthreads();
  for (int i = t; i < NBK; i += 256) {
    int c = lc[i];
    if (c) lc[i] = atomicAdd(&btail[i], c);   // reserve contiguous run
  }
  __syncthreads();
  for (int e = e0 + t; e < e1; e += 256) {
    int d = dst[e];
    int pos = atomicAdd(&lc[d >> 7], 1);
    bspace[pos] = src[e] | (attr[e] << 17) | ((d & 127) << 24);
  }
}

// phase 2: one block per bucket; exact CSR position via LDS cursors seeded
// with off[]; writes confined to the bucket's contiguous ep region.
__global__ __launch_bounds__(256) void k_p2(
    const int* __restrict__ bspace, const int* __restrict__ off,
    int* __restrict__ ep, int N)
{
  __shared__ int lc[128];
  const int b = blockIdx.x, t = threadIdx.x;
  const int nb = b * 128;
  const int nn = min(128, N - nb);
  if (t < nn) lc[t] = off[nb + t];
  __syncthreads();
  const int base = off[nb];
  const int cnt = off[min(nb + 128, N)] - base;
  for (int i = t; i < cnt; i += 256) {
    int p = bspace[base + i];
    int ld = (p >> 24) & 127;
    int pos = atomicAdd(&lc[ld], 1);
    ep[pos] = p & 0xFFFFFF;
  }
}

// agg[i] = sum relu(xb[src] + embb[attr]); bf16 gather (256B rows), fp32 accum
__global__ __launch_bounds__(256) void k_agg(
    const u16* __restrict__ xb, const int* __restrict__ ep,
    const int* __restrict__ off, const u16* __restrict__ embb,
    float* __restrict__ agg, int N)
{
  const int node = blockIdx.x * 4 + (threadIdx.x >> 6);
  if (node >= N) return;
  const int lane = threadIdx.x & 63;
  const int beg = off[node], end = off[node + 1];
  float ax = 0.f, ay = 0.f;
  int e = beg;
  for (; e + 2 <= end; e += 2) {
    int p0 = ep[e], p1 = ep[e + 1];
    int s0 = p0 & 0x1FFFF, a0 = p0 >> 17;
    int s1 = p1 & 0x1FFFF, a1 = p1 >> 17;
    unsigned xu0 = *reinterpret_cast<const unsigned*>(xb + ((size_t)s0 << 7) + lane * 2);
    unsigned eu0 = *reinterpret_cast<const unsigned*>(embb + ((size_t)a0 << 7) + lane * 2);
    unsigned xu1 = *reinterpret_cast<const unsigned*>(xb + ((size_t)s1 << 7) + lane * 2);
    unsigned eu1 = *reinterpret_cast<const unsigned*>(embb + ((size_t)a1 << 7) + lane * 2);
    ax += fmaxf(blo(xu0) + blo(eu0), 0.f);
    ay += fmaxf(bhi(xu0) + bhi(eu0), 0.f);
    ax += fmaxf(blo(xu1) + blo(eu1), 0.f);
    ay += fmaxf(bhi(xu1) + bhi(eu1), 0.f);
  }
  if (e < end) {
    int p = ep[e];
    int s = p & 0x1FFFF, a = p >> 17;
    unsigned xu = *reinterpret_cast<const unsigned*>(xb + ((size_t)s << 7) + lane * 2);
    unsigned eu = *reinterpret_cast<const unsigned*>(embb + ((size_t)a << 7) + lane * 2);
    ax += fmaxf(blo(xu) + blo(eu), 0.f);
    ay += fmaxf(bhi(xu) + bhi(eu), 0.f);
  }
  float2* op = reinterpret_cast<float2*>(agg + (size_t)node * 128 + lane * 2);
  *op = make_float2(ax, ay);
}

// ---------------- launcher ----------------
extern "C" void kernel_launch(void* const* d_in, const int* in_sizes, int n_in,
                              void* d_out, int out_size, void* d_ws, size_t ws_size,
                              hipStream_t stream)
{
  const float* pept  = (const float*)d_in[0];
  const int*   eidx  = (const int*)d_in[1];
  const int*   eattr = (const int*)d_in[2];
  const float* Wp  = (const float*)d_in[3];
  const float* bp  = (const float*)d_in[4];
  const float* emb = (const float*)d_in[5];
  // d_in[6]=cls_token, d_in[7]=cls_edge: dead for the output (CLS node is never
  // a source and row N is dropped) -> skipped.
  const float* W1a = (const float*)d_in[8];
  const float* b1a = (const float*)d_in[9];
  const float* W2a = (const float*)d_in[10];
  const float* b2a = (const float*)d_in[11];
  const float* W1b = (const float*)d_in[12];
  const float* b1b = (const float*)d_in[13];
  const float* W2b = (const float*)d_in[14];
  const float* b2b = (const float*)d_in[15];

  const int N = in_sizes[0] / 512;
  const int E = in_sizes[1] / 2;
  const int* srcp = eidx;
  const int* dstp = eidx + E;

  char* ws = (char*)d_ws;
  const size_t rowBytes = (size_t)N * 128 * 4;
  float* agg = (float*)ws;                          // [N,128] f32
  float* x0  = (float*)(ws + rowBytes);             // [N,128] f32
  char*  p   = ws + 2 * rowBytes;
  u16* tbh   = (u16*)p;             p += (size_t)N * 128 * 2;   // bf16 hidden
  u16* xb    = (u16*)p;             p += (size_t)N * 128 * 2;   // bf16 x mirror
  int* deg    = (int*)p;            p += (size_t)(N + 1) * 4;
  int* off    = (int*)p;            p += (size_t)(N + 1) * 4;
  int* part   = (int*)p;            p += 128 * 4;
  int* btail  = (int*)p;            p += (size_t)((N + 127) / 128) * 4;
  int* ep     = (int*)p;            p += (size_t)E * 4;
  int* bspace = (int*)p;            p += (size_t)E * 4;
  u16* Wpt  = (u16*)p;              p += (size_t)512 * 128 * 2;
  u16* W1at = (u16*)p;              p += (size_t)128 * 128 * 2;
  u16* W2at = (u16*)p;              p += (size_t)128 * 128 * 2;
  u16* W1bt = (u16*)p;              p += (size_t)128 * 128 * 2;
  u16* W2bt = (u16*)p;              p += (size_t)128 * 128 * 2;
  u16* embb = (u16*)p;              p += (size_t)100 * 128 * 2;
  float* x1 = (float*)d_out;
  float* outp = (float*)d_out;

  const int gGemm = (N + 63) / 64;
  const int gE    = (E + 255) / 256;
  const int gAgg  = (N + 3) / 4;
  const int NBsc  = (N + 1023) / 1024;   // scan blocks
  const int NBK   = (N + 127) / 128;     // dst buckets
  const int gP1   = (E + P1_CHUNK - 1) / P1_CHUNK;

  hipLaunchKernelGGL(k_prepw_all,
                     dim3((512 * 128 + 4 * 128 * 128 + 100 * 128 + 255) / 256), dim3(256), 0, stream,
                     Wp, W1a, W2a, W1b, W2b, emb, Wpt, W1at, W2at, W1bt, W2bt, embb);

  // proj: x0 = pept @ Wp + bp  (also emits bf16 mirror xb)
  hipLaunchKernelGGL((k_gemm<512, 0, 0, true>), dim3(gGemm), dim3(256), 0, stream,
                     pept, (const float*)nullptr, Wpt, bp, (const float*)nullptr, x0, xb, N);

  // CSR by dst (built once, reused by both layers)
  hipMemsetAsync(deg, 0, (size_t)(N + 1) * 4, stream);
  hipLaunchKernelGGL(k_hist, dim3(gE), dim3(256), 0, stream, dstp, deg, E);
  hipLaunchKernelGGL(k_scanA, dim3(NBsc), dim3(256), 0, stream, deg, part, N);
  hipLaunchKernelGGL(k_scanB, dim3(1), dim3(128), 0, stream, part, off, NBsc, N);
  hipLaunchKernelGGL(k_scanC, dim3(NBsc), dim3(256), 0, stream, deg, part, off, N);
  hipLaunchKernelGGL(k_binit, dim3((NBK + 255) / 256), dim3(256), 0, stream, off, btail, NBK);
  hipLaunchKernelGGL(k_p1, dim3(gP1), dim3(256), 0, stream,
                     srcp, dstp, eattr, btail, bspace, E, NBK);
  hipLaunchKernelGGL(k_p2, dim3(NBK), dim3(256), 0, stream, bspace, off, ep, N);

  // ---- layer a ----
  hipLaunchKernelGGL(k_agg, dim3(gAgg), dim3(256), 0, stream, xb, ep, off, embb, agg, N);
  hipLaunchKernelGGL((k_gemm<128, 1, 1, false>), dim3(gGemm), dim3(256), 0, stream,
                     x0, agg, W1at, b1a, (const float*)nullptr, tbh, (u16*)nullptr, N);
  hipLaunchKernelGGL((k_gemm<128, 2, 2, true>), dim3(gGemm), dim3(256), 0, stream,
                     tbh, (const float*)nullptr, W2at, b2a, x0, x1, xb, N);

  // ---- layer b ----
  hipLaunchKernelGGL(k_agg, dim3(gAgg), dim3(256), 0, stream, xb, ep, off, embb, agg, N);
  hipLaunchKernelGGL((k_gemm<128, 1, 1, false>), dim3(gGemm), dim3(256), 0, stream,
                     x1, agg, W1bt, b1b, (const float*)nullptr, tbh, (u16*)nullptr, N);
  hipLaunchKernelGGL((k_gemm<128, 2, 2, false>), dim3(gGemm), dim3(256), 0, stream,
                     tbh, (const float*)nullptr, W2bt, b2b, x1, outp, (u16*)nullptr, N);
}

// Round 9
// 428.653 us; speedup vs baseline: 1.9883x; 1.2269x over previous
//
#include <hip/hip_runtime.h>

typedef unsigned short u16;
typedef __attribute__((ext_vector_type(8))) short short8v;
typedef __attribute__((ext_vector_type(4))) float f32x4;

__device__ __forceinline__ u16 f2b(float f) {
  union { float fv; unsigned int i; } v; v.fv = f;
  unsigned int x = v.i;
  return (u16)((x + 0x7FFFu + ((x >> 16) & 1u)) >> 16);
}
__device__ __forceinline__ float bs2f(u16 u) {
  union { unsigned i; float f; } v; v.i = (unsigned)u << 16; return v.f;
}
__device__ __forceinline__ float blo(unsigned u) {
  union { unsigned i; float f; } v; v.i = u << 16; return v.f;
}
__device__ __forceinline__ float bhi(unsigned u) {
  union { unsigned i; float f; } v; v.i = u & 0xFFFF0000u; return v.f;
}

// ---------------- weight + emb prep (one launch) ----------------
__global__ __launch_bounds__(256) void k_prepw_all(
    const float* __restrict__ Wp, const float* __restrict__ W1a,
    const float* __restrict__ W2a, const float* __restrict__ W1b,
    const float* __restrict__ W2b, const float* __restrict__ emb,
    u16* __restrict__ Wpt, u16* __restrict__ W1at, u16* __restrict__ W2at,
    u16* __restrict__ W1bt, u16* __restrict__ W2bt, u16* __restrict__ embb)
{
  int idx = blockIdx.x * 256 + threadIdx.x;
  if (idx < 512 * 128) {
    int k = idx >> 7, c = idx & 127;
    Wpt[(size_t)c * 512 + k] = f2b(Wp[idx]);
    return;
  }
  idx -= 512 * 128;
  if (idx < 4 * 128 * 128) {
    int w = idx >> 14, r = idx & (128 * 128 - 1);
    int k = r >> 7, c = r & 127;
    const float* s = (w == 0) ? W1a : (w == 1) ? W2a : (w == 2) ? W1b : W2b;
    u16* d = (w == 0) ? W1at : (w == 1) ? W2at : (w == 2) ? W1bt : W2bt;
    d[(size_t)c * 128 + k] = f2b(s[r]);
    return;
  }
  idx -= 4 * 128 * 128;
  if (idx < 100 * 128) embb[idx] = f2b(emb[idx]);
}

// ---------------- MFMA GEMM, BM=64: out[N,128] = A[N,KTOT] @ W[KTOT,128] ----
// STAGE: 0 = A fp32, 2 = A bf16
// EPI: 0 = bf16 out, 1 = relu -> bf16 out, 2 = +resb -> bf16 out, 3 = +resb -> f32 out
template <int KTOT, int STAGE, int EPI>
__global__ __launch_bounds__(256) void k_gemm(
    const void* __restrict__ Ain, const u16* __restrict__ Wt,
    const float* __restrict__ bias, const u16* __restrict__ resb,
    void* __restrict__ outp, int N)
{
  __shared__ u16 As[64 * 64];    // [r][k0..k0+64), row stride 128B, ^((r&7)<<4)
  __shared__ u16 Bs[128 * 64];
  const int t = threadIdx.x;
  const int row0 = blockIdx.x * 64;
  const int lane = t & 63;
  const int wave = t >> 6;
  const int wm = wave >> 1, wn = wave & 1;   // 2x2 waves: 32 rows x 64 cols each
  const int colg = lane & 15, rowg = lane >> 4;

  f32x4 acc[2][4];
#pragma unroll
  for (int ni = 0; ni < 4; ++ni) {
    float bc = bias[wn * 64 + ni * 16 + colg];
#pragma unroll
    for (int mi = 0; mi < 2; ++mi) acc[mi][ni] = (f32x4){bc, bc, bc, bc};
  }

  for (int k0 = 0; k0 < KTOT; k0 += 64) {
    if (STAGE == 0) {
      const float* A = (const float*)Ain;
#pragma unroll
      for (int i = 0; i < 4; ++i) {
        int idx = t + i * 256;            // 1024 float4 = 64 rows x 16
        int r = idx >> 4, kq = idx & 15;
        float4 v = make_float4(0.f, 0.f, 0.f, 0.f);
        if (row0 + r < N)
          v = *reinterpret_cast<const float4*>(A + (size_t)(row0 + r) * KTOT + k0 + kq * 4);
        ushort4 b;
        b.x = f2b(v.x); b.y = f2b(v.y); b.z = f2b(v.z); b.w = f2b(v.w);
        int byteoff = (r * 128 + kq * 8) ^ ((r & 7) << 4);
        *reinterpret_cast<ushort4*>((char*)As + byteoff) = b;
      }
    } else {
      const u16* A = (const u16*)Ain;
#pragma unroll
      for (int i = 0; i < 2; ++i) {
        int idx = t + i * 256;            // 512 int4 = 64 rows x 8
        int r = idx >> 3, k8 = idx & 7;
        int4 v = make_int4(0, 0, 0, 0);
        if (row0 + r < N)
          v = *reinterpret_cast<const int4*>(A + (size_t)(row0 + r) * KTOT + k0 + k8 * 8);
        int byteoff = (r * 128 + k8 * 16) ^ ((r & 7) << 4);
        *reinterpret_cast<int4*>((char*)As + byteoff) = v;
      }
    }
#pragma unroll
    for (int i = 0; i < 4; ++i) {
      int idx = t + i * 256;              // 1024 int4 = 128 cols x 8
      int c = idx >> 3, k8 = idx & 7;
      int4 v = *reinterpret_cast<const int4*>(Wt + (size_t)c * KTOT + k0 + k8 * 8);
      int byteoff = (c * 128 + k8 * 16) ^ ((c & 7) << 4);
      *reinterpret_cast<int4*>((char*)Bs + byteoff) = v;
    }
    __syncthreads();
#pragma unroll
    for (int kk = 0; kk < 64; kk += 32) {
      short8v a[2], b[4];
#pragma unroll
      for (int mi = 0; mi < 2; ++mi) {
        int r = wm * 32 + mi * 16 + colg;
        int byteoff = (r * 128 + (kk + rowg * 8) * 2) ^ ((r & 7) << 4);
        a[mi] = *reinterpret_cast<const short8v*>((const char*)As + byteoff);
      }
#pragma unroll
      for (int ni = 0; ni < 4; ++ni) {
        int c = wn * 64 + ni * 16 + colg;
        int byteoff = (c * 128 + (kk + rowg * 8) * 2) ^ ((c & 7) << 4);
        b[ni] = *reinterpret_cast<const short8v*>((const char*)Bs + byteoff);
      }
#pragma unroll
      for (int mi = 0; mi < 2; ++mi)
#pragma unroll
        for (int ni = 0; ni < 4; ++ni)
          acc[mi][ni] = __builtin_amdgcn_mfma_f32_16x16x32_bf16(a[mi], b[ni], acc[mi][ni], 0, 0, 0);
    }
    __syncthreads();
  }

#pragma unroll
  for (int mi = 0; mi < 2; ++mi) {
#pragma unroll
    for (int j = 0; j < 4; ++j) {
      int row = row0 + wm * 32 + mi * 16 + rowg * 4 + j;
      if (row >= N) continue;
#pragma unroll
      for (int ni = 0; ni < 4; ++ni) {
        int col = wn * 64 + ni * 16 + colg;
        float v = acc[mi][ni][j];
        if (EPI == 0) {
          ((u16*)outp)[(size_t)row * 128 + col] = f2b(v);
        } else if (EPI == 1) {
          ((u16*)outp)[(size_t)row * 128 + col] = f2b(fmaxf(v, 0.f));
        } else {
          v += bs2f(resb[(size_t)row * 128 + col]);
          if (EPI == 2) ((u16*)outp)[(size_t)row * 128 + col] = f2b(v);
          else          ((float*)outp)[(size_t)row * 128 + col] = v;
        }
      }
    }
  }
}

// ---------------- CSR build ----------------
__global__ __launch_bounds__(256) void k_hist(
    const int* __restrict__ dst, int* __restrict__ deg, int nE)
{
  int e = blockIdx.x * 256 + threadIdx.x;
  if (e < nE) atomicAdd(&deg[dst[e]], 1);
}

__global__ __launch_bounds__(256) void k_scanA(
    const int* __restrict__ deg, int* __restrict__ part, int N)
{
  const int b = blockIdx.x, t = threadIdx.x;
  const int lane = t & 63, wave = t >> 6;
  int base = b * 1024 + t * 4;
  int s = 0;
#pragma unroll
  for (int i = 0; i < 4; ++i) { int j = base + i; if (j < N) s += deg[j]; }
  int v = s;
  for (int d = 1; d < 64; d <<= 1) { int u = __shfl_up(v, d); if (lane >= d) v += u; }
  __shared__ int wsum[4];
  if (lane == 63) wsum[wave] = v;
  __syncthreads();
  if (t == 0) part[b] = wsum[0] + wsum[1] + wsum[2] + wsum[3];
}

__global__ __launch_bounds__(128) void k_scanB(
    int* __restrict__ part, int* __restrict__ off, int NB, int N)
{
  __shared__ int ps[128];
  const int t = threadIdx.x;
  int v0 = (t < NB) ? part[t] : 0;
  ps[t] = v0;
  __syncthreads();
  for (int d = 1; d < 128; d <<= 1) {
    int u = (t >= d) ? ps[t - d] : 0;
    __syncthreads();
    ps[t] += u;
    __syncthreads();
  }
  if (t < NB) part[t] = ps[t] - v0;
  if (t == 127) off[N] = ps[127];
}

__global__ __launch_bounds__(256) void k_scanC(
    const int* __restrict__ deg, const int* __restrict__ part,
    int* __restrict__ off, int N)
{
  const int b = blockIdx.x, t = threadIdx.x;
  const int lane = t & 63, wave = t >> 6;
  int base = b * 1024 + t * 4;
  int d0 = 0, d1 = 0, d2 = 0, d3 = 0;
  if (base + 0 < N) d0 = deg[base + 0];
  if (base + 1 < N) d1 = deg[base + 1];
  if (base + 2 < N) d2 = deg[base + 2];
  if (base + 3 < N) d3 = deg[base + 3];
  int s = d0 + d1 + d2 + d3;
  int v = s;
  for (int dd = 1; dd < 64; dd <<= 1) { int u = __shfl_up(v, dd); if (lane >= dd) v += u; }
  int excl = v - s;
  __shared__ int wsum[4];
  if (lane == 63) wsum[wave] = v;
  __syncthreads();
  int wbase = 0;
  for (int w = 0; w < wave; ++w) wbase += wsum[w];
  int run = part[b] + wbase + excl;
  if (base + 0 < N) { off[base + 0] = run; run += d0; }
  if (base + 1 < N) { off[base + 1] = run; run += d1; }
  if (base + 2 < N) { off[base + 2] = run; run += d2; }
  if (base + 3 < N) { off[base + 3] = run; run += d3; }
}

// btail[b] = off[b*128]  (bucket write tails for phase-1)
__global__ __launch_bounds__(256) void k_binit(
    const int* __restrict__ off, int* __restrict__ btail, int NBK)
{
  int b = blockIdx.x * 256 + threadIdx.x;
  if (b < NBK) btail[b] = off[b * 128];
}

// phase 1: bin edges into 128-node dst-buckets via per-block LDS histogram +
// ONE bulk atomic reservation per (block,bucket).
// payload = src | attr<<17 | (dst&127)<<24
#define P1_CHUNK 4096
__global__ __launch_bounds__(256) void k_p1(
    const int* __restrict__ src, const int* __restrict__ dst,
    const int* __restrict__ attr, int* __restrict__ btail,
    int* __restrict__ bspace, int nE, int NBK)
{
  __shared__ int lc[1024];          // NBK <= 1024 (N <= 131072)
  const int t = threadIdx.x;
  const int e0 = blockIdx.x * P1_CHUNK;
  const int e1 = min(e0 + P1_CHUNK, nE);
  for (int i = t; i < NBK; i += 256) lc[i] = 0;
  __syncthreads();
  for (int e = e0 + t; e < e1; e += 256) atomicAdd(&lc[dst[e] >> 7], 1);
  __syncthreads();
  for (int i = t; i < NBK; i += 256) {
    int c = lc[i];
    if (c) lc[i] = atomicAdd(&btail[i], c);   // reserve contiguous run
  }
  __syncthreads();
  for (int e = e0 + t; e < e1; e += 256) {
    int d = dst[e];
    int pos = atomicAdd(&lc[d >> 7], 1);
    bspace[pos] = src[e] | (attr[e] << 17) | ((d & 127) << 24);
  }
}

// phase 2: one block per bucket; exact CSR position via LDS cursors.
__global__ __launch_bounds__(256) void k_p2(
    const int* __restrict__ bspace, const int* __restrict__ off,
    int* __restrict__ ep, int N)
{
  __shared__ int lc[128];
  const int b = blockIdx.x, t = threadIdx.x;
  const int nb = b * 128;
  const int nn = min(128, N - nb);
  if (t < nn) lc[t] = off[nb + t];
  __syncthreads();
  const int base = off[nb];
  const int cnt = off[min(nb + 128, N)] - base;
  for (int i = t; i < cnt; i += 256) {
    int p = bspace[base + i];
    int ld = (p >> 24) & 127;
    int pos = atomicAdd(&lc[ld], 1);
    ep[pos] = p & 0xFFFFFF;
  }
}

// am[i] = bf16( xb[i] + sum_{e in-edges(i)} relu(xb[src]+embb[attr]) )
// = the ready-to-use bf16 A-matrix for gemm1. One wave/node, unroll-4 gather.
__global__ __launch_bounds__(256) void k_aggA(
    const u16* __restrict__ xb, const int* __restrict__ ep,
    const int* __restrict__ off, const u16* __restrict__ embb,
    u16* __restrict__ am, int N)
{
  const int node = blockIdx.x * 4 + (threadIdx.x >> 6);
  if (node >= N) return;
  const int lane = threadIdx.x & 63;
  const int beg = off[node], end = off[node + 1];
  float ax = 0.f, ay = 0.f;
  int e = beg;
  for (; e + 4 <= end; e += 4) {
    int p0 = ep[e], p1 = ep[e + 1], p2 = ep[e + 2], p3 = ep[e + 3];
    unsigned xu0 = *reinterpret_cast<const unsigned*>(xb + ((size_t)(p0 & 0x1FFFF) << 7) + lane * 2);
    unsigned eu0 = *reinterpret_cast<const unsigned*>(embb + ((size_t)(p0 >> 17) << 7) + lane * 2);
    unsigned xu1 = *reinterpret_cast<const unsigned*>(xb + ((size_t)(p1 & 0x1FFFF) << 7) + lane * 2);
    unsigned eu1 = *reinterpret_cast<const unsigned*>(embb + ((size_t)(p1 >> 17) << 7) + lane * 2);
    unsigned xu2 = *reinterpret_cast<const unsigned*>(xb + ((size_t)(p2 & 0x1FFFF) << 7) + lane * 2);
    unsigned eu2 = *reinterpret_cast<const unsigned*>(embb + ((size_t)(p2 >> 17) << 7) + lane * 2);
    unsigned xu3 = *reinterpret_cast<const unsigned*>(xb + ((size_t)(p3 & 0x1FFFF) << 7) + lane * 2);
    unsigned eu3 = *reinterpret_cast<const unsigned*>(embb + ((size_t)(p3 >> 17) << 7) + lane * 2);
    ax += fmaxf(blo(xu0) + blo(eu0), 0.f);
    ay += fmaxf(bhi(xu0) + bhi(eu0), 0.f);
    ax += fmaxf(blo(xu1) + blo(eu1), 0.f);
    ay += fmaxf(bhi(xu1) + bhi(eu1), 0.f);
    ax += fmaxf(blo(xu2) + blo(eu2), 0.f);
    ay += fmaxf(bhi(xu2) + bhi(eu2), 0.f);
    ax += fmaxf(blo(xu3) + blo(eu3), 0.f);
    ay += fmaxf(bhi(xu3) + bhi(eu3), 0.f);
  }
  for (; e < end; ++e) {
    int p = ep[e];
    unsigned xu = *reinterpret_cast<const unsigned*>(xb + ((size_t)(p & 0x1FFFF) << 7) + lane * 2);
    unsigned eu = *reinterpret_cast<const unsigned*>(embb + ((size_t)(p >> 17) << 7) + lane * 2);
    ax += fmaxf(blo(xu) + blo(eu), 0.f);
    ay += fmaxf(bhi(xu) + bhi(eu), 0.f);
  }
  unsigned xo = *reinterpret_cast<const unsigned*>(xb + ((size_t)node << 7) + lane * 2);
  ax += blo(xo);
  ay += bhi(xo);
  unsigned w = ((unsigned)f2b(ay) << 16) | (unsigned)f2b(ax);
  *reinterpret_cast<unsigned*>(am + ((size_t)node << 7) + lane * 2) = w;
}

// ---------------- launcher ----------------
extern "C" void kernel_launch(void* const* d_in, const int* in_sizes, int n_in,
                              void* d_out, int out_size, void* d_ws, size_t ws_size,
                              hipStream_t stream)
{
  const float* pept  = (const float*)d_in[0];
  const int*   eidx  = (const int*)d_in[1];
  const int*   eattr = (const int*)d_in[2];
  const float* Wp  = (const float*)d_in[3];
  const float* bp  = (const float*)d_in[4];
  const float* emb = (const float*)d_in[5];
  // d_in[6]=cls_token, d_in[7]=cls_edge: dead for the output (CLS node is never
  // a source and row N is dropped) -> skipped.
  const float* W1a = (const float*)d_in[8];
  const float* b1a = (const float*)d_in[9];
  const float* W2a = (const float*)d_in[10];
  const float* b2a = (const float*)d_in[11];
  const float* W1b = (const float*)d_in[12];
  const float* b1b = (const float*)d_in[13];
  const float* W2b = (const float*)d_in[14];
  const float* b2b = (const float*)d_in[15];

  const int N = in_sizes[0] / 512;
  const int E = in_sizes[1] / 2;
  const int* srcp = eidx;
  const int* dstp = eidx + E;

  char* ws = (char*)d_ws;
  char* p = ws;
  u16* xb  = (u16*)p;               p += (size_t)N * 128 * 2;   // bf16 x master
  u16* am  = (u16*)p;               p += (size_t)N * 128 * 2;   // bf16 A for gemm1
  u16* tbh = (u16*)p;               p += (size_t)N * 128 * 2;   // bf16 hidden
  int* deg    = (int*)p;            p += (size_t)(N + 1) * 4;
  int* off    = (int*)p;            p += (size_t)(N + 1) * 4;
  int* part   = (int*)p;            p += 128 * 4;
  int* btail  = (int*)p;            p += (size_t)((N + 127) / 128) * 4;
  int* ep     = (int*)p;            p += (size_t)E * 4;
  int* bspace = (int*)p;            p += (size_t)E * 4;
  u16* Wpt  = (u16*)p;              p += (size_t)512 * 128 * 2;
  u16* W1at = (u16*)p;              p += (size_t)128 * 128 * 2;
  u16* W2at = (u16*)p;              p += (size_t)128 * 128 * 2;
  u16* W1bt = (u16*)p;              p += (size_t)128 * 128 * 2;
  u16* W2bt = (u16*)p;              p += (size_t)128 * 128 * 2;
  u16* embb = (u16*)p;              p += (size_t)100 * 128 * 2;

  const int gGemm = (N + 63) / 64;
  const int gE    = (E + 255) / 256;
  const int gAgg  = (N + 3) / 4;
  const int NBsc  = (N + 1023) / 1024;   // scan blocks
  const int NBK   = (N + 127) / 128;     // dst buckets
  const int gP1   = (E + P1_CHUNK - 1) / P1_CHUNK;

  hipLaunchKernelGGL(k_prepw_all,
                     dim3((512 * 128 + 4 * 128 * 128 + 100 * 128 + 255) / 256), dim3(256), 0, stream,
                     Wp, W1a, W2a, W1b, W2b, emb, Wpt, W1at, W2at, W1bt, W2bt, embb);

  // proj: xb = bf16(pept @ Wp + bp)
  hipLaunchKernelGGL((k_gemm<512, 0, 0>), dim3(gGemm), dim3(256), 0, stream,
                     pept, Wpt, bp, (const u16*)nullptr, xb, N);

  // CSR by dst (built once, reused by both layers)
  hipMemsetAsync(deg, 0, (size_t)(N + 1) * 4, stream);
  hipLaunchKernelGGL(k_hist, dim3(gE), dim3(256), 0, stream, dstp, deg, E);
  hipLaunchKernelGGL(k_scanA, dim3(NBsc), dim3(256), 0, stream, deg, part, N);
  hipLaunchKernelGGL(k_scanB, dim3(1), dim3(128), 0, stream, part, off, NBsc, N);
  hipLaunchKernelGGL(k_scanC, dim3(NBsc), dim3(256), 0, stream, deg, part, off, N);
  hipLaunchKernelGGL(k_binit, dim3((NBK + 255) / 256), dim3(256), 0, stream, off, btail, NBK);
  hipLaunchKernelGGL(k_p1, dim3(gP1), dim3(256), 0, stream,
                     srcp, dstp, eattr, btail, bspace, E, NBK);
  hipLaunchKernelGGL(k_p2, dim3(NBK), dim3(256), 0, stream, bspace, off, ep, N);

  // ---- layer a ----
  hipLaunchKernelGGL(k_aggA, dim3(gAgg), dim3(256), 0, stream, xb, ep, off, embb, am, N);
  hipLaunchKernelGGL((k_gemm<128, 2, 1>), dim3(gGemm), dim3(256), 0, stream,
                     am, W1at, b1a, (const u16*)nullptr, tbh, N);
  hipLaunchKernelGGL((k_gemm<128, 2, 2>), dim3(gGemm), dim3(256), 0, stream,
                     tbh, W2at, b2a, xb, xb, N);   // in-place residual update of xb

  // ---- layer b ----
  hipLaunchKernelGGL(k_aggA, dim3(gAgg), dim3(256), 0, stream, xb, ep, off, embb, am, N);
  hipLaunchKernelGGL((k_gemm<128, 2, 1>), dim3(gGemm), dim3(256), 0, stream,
                     am, W1bt, b1b, (const u16*)nullptr, tbh, N);
  hipLaunchKernelGGL((k_gemm<128, 2, 3>), dim3(gGemm), dim3(256), 0, stream,
                     tbh, W2bt, b2b, xb, d_out, N); // final: f32 out
}